// Round 6
// baseline (120.699 us; speedup 1.0000x reference)
//
#include <hip/hip_runtime.h>

// SSIM (window=3, stride=3, pad=1) on (16,3,512,512) fp32 -> scalar mean.
// V6: V5's coalesced wave-cooperative scheme, split to HALF-ROW waves.
// V5 post-mortem: main ~33us (vs ~16us HBM floor) with ~150 VGPR -> only
// ~12 waves/CU and 2.7 occupancy rounds; bursty load->stall->compute waves
// leave the memory pipe idle in windows. Here one wave covers 256 output
// cols (lane = one f4 per row per image, 6 x 1KB coalesced loads, 24 data
// VGPRs); the straddling bin at the half boundary is served by 6 uniform
// 16B broadcast loads of slot 63 (replaces V5's fwd-seam shuffles); the
// left half's "previous f4" is implicit zeros, which also implements the
// left pad. 16416 waves, ~4-5 rounds, VGPR ~110 -> 4-5 waves/SIMD.

#define HW       512
#define PLANE_SZ (HW * HW)
#define OHW      171                    // (512 + 2 - 3)/3 + 1
#define NPLANE   48                     // 16 batch * 3 channels
#define NOUT     (NPLANE * OHW * OHW)   // 1,403,568
#define NTASK    (NPLANE * OHW * 2)     // 16416 half-row wave-tasks
#define TPB      256
#define WPB      4
#define NBLK     (NTASK / WPB)          // 4104 (exact)

typedef float f4 __attribute__((ext_vector_type(4)));

__device__ __forceinline__ float ssim_val(float s1, float s2, float s11,
                                          float s22, float s12) {
  const float C1 = 1e-4f, C2 = 9e-4f;
  const float m11 = s1 * s1, m22 = s2 * s2, m12 = s1 * s2;
  const float sg1 = s11 - m11, sg2 = s22 - m22, sg12 = s12 - m12;
  const float num = (2.0f * m12 + C1) * (2.0f * sg12 + C2);
  const float den = (m11 + m22 + C1) * (sg1 + sg2 + C2);
  return num * __builtin_amdgcn_rcpf(den);   // rel err ~1e-7 << 2.4e-4 thr
}

__global__ __launch_bounds__(TPB) void ssim_main(
    const float* __restrict__ img1, const float* __restrict__ img2,
    const float* __restrict__ win, float* __restrict__ partial) {
  const int lane = threadIdx.x & 63;
  const int wv   = threadIdx.x >> 6;
  const int task = blockIdx.x * WPB + wv;      // < 16416 (grid exact)
  const int plane = task / (2 * OHW);
  const int rem   = task - plane * (2 * OHW);
  const int oy    = rem >> 1;
  const int h     = rem & 1;                   // half: cols 256h..256h+255

  // Separable window: w[3r+c] = wy[r]*wx[c].
  float wy[3], wx[3];
#pragma unroll
  for (int k = 0; k < 3; ++k) {
    wy[k] = win[3 * k] + win[3 * k + 1] + win[3 * k + 2];
    wx[k] = win[k] + win[k + 3] + win[k + 6];
  }
  const int r0 = 3 * oy - 1;
  float wyv[3];
  wyv[0] = (r0 >= 0) ? wy[0] : 0.0f;           // oy==0: zero-weight top row
  wyv[1] = wy[1];
  wyv[2] = wy[2];
  const int rr0 = (r0 < 0) ? 0 : r0;

  const float* a = img1 + (size_t)plane * PLANE_SZ;
  const float* b = img2 + (size_t)plane * PLANE_SZ;

  // ---- load phase ----
  f4 xa[3], xb[3], pa[3], pb[3];
  const f4* ra0;
#pragma unroll
  for (int k = 0; k < 3; ++k) {
    const int r = (k == 0) ? rr0 : (r0 + k);
    const f4* ra = (const f4*)(a + (size_t)r * HW);
    const f4* rb = (const f4*)(b + (size_t)r * HW);
    const int s = 64 * h + lane;
    xa[k] = ra[s];
    xb[k] = rb[s];
    if (h) {                                    // uniform branch per wave
      pa[k] = ra[63];                           // cols 252..255 (broadcast)
      pb[k] = rb[63];
    } else {
      pa[k] = (f4){0.f, 0.f, 0.f, 0.f};         // left pad: virtual zeros
      pb[k] = (f4){0.f, 0.f, 0.f, 0.f};
    }
    (void)ra0;
  }

  // ---- row collapse (lane f4) ----
  float P1[4] = {0,0,0,0}, P2[4] = {0,0,0,0}, P11[4] = {0,0,0,0},
        P22[4] = {0,0,0,0}, P12[4] = {0,0,0,0};
#pragma unroll
  for (int k = 0; k < 3; ++k) {
    const float wyk = wyv[k];
#pragma unroll
    for (int j = 0; j < 4; ++j) {
      const float x = xa[k][j], y = xb[k][j];
      const float u = wyk * x, v = wyk * y;
      P1[j] += u;  P2[j] += v;
      P11[j] = fmaf(u, x, P11[j]);
      P22[j] = fmaf(v, y, P22[j]);
      P12[j] = fmaf(u, y, P12[j]);
    }
  }

  // m for this lane's f4 (c0 = 256h + 4*lane; 256%3==1): m=(h+lane)%3
  const int m = (h + lane) % 3;
  // col c0+j uses wx[(c0+j+1)%3] = wx[(m+j+1)%3]
  float wxl[4];
#pragma unroll
  for (int j = 0; j < 4; ++j) {
    const int ix = (m + j + 1) % 3;
    wxl[j] = (ix == 0) ? wx[0] : ((ix == 1) ? wx[1] : wx[2]);
  }
  // left-mask: m==0 ->{1,1,0,0}, m==1 ->{1,0,0,0}, m==2 ->{1,1,1,0}
  const float aL = (m != 1) ? 1.0f : 0.0f;
  const float bL = (m == 2) ? 1.0f : 0.0f;

  float L[5], R[5];
  {
    float t0, t1, t2, t3, full, left;
#define BIN(Q, PP)                                             \
    t0 = wxl[0] * PP[0]; t1 = wxl[1] * PP[1];                  \
    t2 = wxl[2] * PP[2]; t3 = wxl[3] * PP[3];                  \
    full = (t0 + t1) + (t2 + t3);                              \
    left = fmaf(bL, t2, fmaf(aL, t1, t0));                     \
    L[Q] = left; R[Q] = full - left;
    BIN(0, P1) BIN(1, P2) BIN(2, P11) BIN(3, P22) BIN(4, P12)
#undef BIN
  }

  // ---- R_prev: right partial of the straddling f4 (cols 256h-4..256h-1),
  // uniform across lanes. m' = (256h-4)%3 = (h+2)%3.
  float Rp[5] = {0.f, 0.f, 0.f, 0.f, 0.f};
  if (h) {                                      // uniform branch
    float Q1[4] = {0,0,0,0}, Q2[4] = {0,0,0,0}, Q11[4] = {0,0,0,0},
          Q22[4] = {0,0,0,0}, Q12[4] = {0,0,0,0};
#pragma unroll
    for (int k = 0; k < 3; ++k) {
      const float wyk = wyv[k];
#pragma unroll
      for (int j = 0; j < 4; ++j) {
        const float x = pa[k][j], y = pb[k][j];
        const float u = wyk * x, v = wyk * y;
        Q1[j] += u;  Q2[j] += v;
        Q11[j] = fmaf(u, x, Q11[j]);
        Q22[j] = fmaf(v, y, Q22[j]);
        Q12[j] = fmaf(u, y, Q12[j]);
      }
    }
    const int mp = (h + 2) % 3;                 // == 0 for h==1
    float wxp[4];
#pragma unroll
    for (int j = 0; j < 4; ++j) {
      const int ix = (mp + j + 1) % 3;
      wxp[j] = (ix == 0) ? wx[0] : ((ix == 1) ? wx[1] : wx[2]);
    }
    const float aP = (mp != 1) ? 1.0f : 0.0f;
    const float bP = (mp == 2) ? 1.0f : 0.0f;
    float t0, t1, t2, t3, full, left;
#define BINP(Q, PP)                                            \
    t0 = wxp[0] * PP[0]; t1 = wxp[1] * PP[1];                  \
    t2 = wxp[2] * PP[2]; t3 = wxp[3] * PP[3];                  \
    full = (t0 + t1) + (t2 + t3);                              \
    left = fmaf(bP, t2, fmaf(aP, t1, t0));                     \
    Rp[Q] = full - left;
    BINP(0, Q1) BINP(1, Q2) BINP(2, Q11) BINP(3, Q22) BINP(4, Q12)
#undef BINP
  }

  // ---- merge: L takes previous lane's R when incomplete (m != 2);
  // lane 0's "previous" is Rp (zeros for h==0 -> also the left pad).
  const float allow = (m != 2) ? 1.0f : 0.0f;
#pragma unroll
  for (int q = 0; q < 5; ++q) {
    float up = __shfl_up(R[q], 1, 64);
    if (lane == 0) up = Rp[q];
    L[q] = fmaf(allow, up, L[q]);
  }

  // ---- finalize: L always owned; R owned iff m == 1 (complete in-lane) ----
  float acc = ssim_val(L[0], L[1], L[2], L[3], L[4]);
  if (m == 1) acc += ssim_val(R[0], R[1], R[2], R[3], R[4]);

  // wave reduce -> LDS -> one write per block (proven pattern)
#pragma unroll
  for (int off = 32; off > 0; off >>= 1) acc += __shfl_down(acc, off, 64);
  __shared__ float wsum[TPB / 64];
  if (lane == 0) wsum[wv] = acc;
  __syncthreads();
  if (threadIdx.x == 0) {
    float s = 0.f;
#pragma unroll
    for (int i = 0; i < TPB / 64; ++i) s += wsum[i];
    partial[blockIdx.x] = s;   // every block writes its slot: no init needed
  }
}

__global__ __launch_bounds__(256) void ssim_final(
    const float* __restrict__ partial, float* __restrict__ out) {
  double acc = 0.0;
  for (int i = threadIdx.x; i < NBLK; i += 256) acc += (double)partial[i];
#pragma unroll
  for (int off = 32; off > 0; off >>= 1) acc += __shfl_down(acc, off, 64);
  __shared__ double wsum[4];
  const int lane = threadIdx.x & 63, wid = threadIdx.x >> 6;
  if (lane == 0) wsum[wid] = acc;
  __syncthreads();
  if (threadIdx.x == 0) {
    double s = 0.0;
#pragma unroll
    for (int i = 0; i < 4; ++i) s += wsum[i];
    out[0] = (float)(s / (double)NOUT);
  }
}

extern "C" void kernel_launch(void* const* d_in, const int* in_sizes, int n_in,
                              void* d_out, int out_size, void* d_ws, size_t ws_size,
                              hipStream_t stream) {
  const float* img1 = (const float*)d_in[0];
  const float* img2 = (const float*)d_in[1];
  const float* win  = (const float*)d_in[2];
  float* partial = (float*)d_ws;   // NBLK floats
  float* out = (float*)d_out;

  ssim_main<<<NBLK, TPB, 0, stream>>>(img1, img2, win, partial);
  ssim_final<<<1, 256, 0, stream>>>(partial, out);
}